// Round 4
// baseline (23673.697 us; speedup 1.0000x reference)
//
#include <hip/hip_runtime.h>

typedef unsigned short ushort_t;
typedef unsigned int uint_t;
typedef unsigned long long u64_t;
typedef float f4v __attribute__((ext_vector_type(4)));

// Problem dims: B=32 N=256 T=13 CIN=2 HID=64 EMB=10 K=2
// Output: float32, (B,N,13,HID)
// ws layout (well under the 21,823,488 B footprint):
#define CW_OFF  0          // canonical fp32 inputs (524288 B)
#define WN_OFF  851968     // Wn bf16 256x2x64x64 (4 MB), each block writes/reads its own 32-n slice
#define XB_OFF  5046272    // XB bf16 2 x (8192x64) x-exchange double buffer (2 MB)

// float-element offsets inside canonical region F
#define F_X0     0
#define F_WH     16384
#define F_BH     16512
#define F_WZ     16576
#define F_BZ     16704
#define F_WFIN   16768
#define F_BFIN   20864
#define F_WFHID  20928
#define F_BFHID  25024
#define F_WFOUT  25088
#define F_BFOUT  33280
#define F_WGIN   33408
#define F_BGIN   37504
#define F_WGOUT  37568
#define F_BGOUT  45760
#define F_EG     45888
#define F_WPOOL  48448
#define F_BPOOL  130368

// per-bb (batch sample) barrier counters, monotone within a launch.
// g_bar[bb*64] to give each its own 256B line. Reset by k_conv each launch.
__device__ int g_bar[2048];

__device__ __forceinline__ float bfl(uint_t u){ union{uint_t i; float f;} c; c.i = u<<16; return c.f; }
__device__ __forceinline__ float bfh(uint_t u){ union{uint_t i; float f;} c; c.i = u & 0xffff0000u; return c.f; }
__device__ __forceinline__ float bf1(ushort_t u){ union{uint_t i; float f;} c; c.i = ((uint_t)u)<<16; return c.f; }
__device__ __forceinline__ uint_t f2bf(float x){
  uint_t u = __float_as_uint(x);
  uint_t r = u + 0x7fffu + ((u >> 16) & 1u);
  return r >> 16;
}
__device__ __forceinline__ float fast_tanh(float x){
  float e = __expf(2.0f*x);
  return 1.0f - 2.0f/(e+1.0f);
}
__device__ __forceinline__ bool inputs_are_f32(const void* times){
  return ((const uint_t*)times)[0] != 0x3F800000u;
}
__device__ __forceinline__ void ntst4(float* p, float a, float b, float c, float d){
  f4v v; v[0]=a; v[1]=b; v[2]=c; v[3]=d;
  __builtin_nontemporal_store(v, (f4v*)p);
}
// agent-scope (device-coherent) 8B access for the cross-XCD x-exchange.
// Scoped atomics read/write the coherent point — no cache-invalidate fences
// needed, so the block's L1/L2-resident weights stay hot.
__device__ __forceinline__ u64_t xload(const ushort_t* p){
  return __hip_atomic_load((const u64_t*)p, __ATOMIC_RELAXED, __HIP_MEMORY_SCOPE_AGENT);
}
__device__ __forceinline__ void xstore(ushort_t* p, u64_t v){
  __hip_atomic_store((u64_t*)p, v, __ATOMIC_RELAXED, __HIP_MEMORY_SCOPE_AGENT);
}

// acc[0..3] += sum_i act[i] * W[i*64 + o0 + j]   (W fp32, row stride 64)
__device__ __forceinline__ void dotf_4(const float* act, const float* W, int o0, float acc[4]) {
  const float4* a4 = (const float4*)act;
  #pragma unroll
  for (int i4 = 0; i4 < 16; ++i4) {
    float4 av4 = a4[i4];
    float av[4] = {av4.x, av4.y, av4.z, av4.w};
    #pragma unroll
    for (int ii = 0; ii < 4; ++ii) {
      float4 w = *(const float4*)(W + (i4*4+ii)*64 + o0);
      acc[0] += av[ii]*w.x; acc[1] += av[ii]*w.y;
      acc[2] += av[ii]*w.z; acc[3] += av[ii]*w.w;
    }
  }
}

// acc[0..7] += sum_i act[i] * W[i*128 + co0 + j]  (W fp32, row stride 128)
__device__ __forceinline__ void dotf_8(const float* act, const float* W, int co0, float acc[8]) {
  const float4* a4 = (const float4*)act;
  #pragma unroll
  for (int i4 = 0; i4 < 16; ++i4) {
    float4 av4 = a4[i4];
    float av[4] = {av4.x, av4.y, av4.z, av4.w};
    #pragma unroll
    for (int ii = 0; ii < 4; ++ii) {
      const float* wp = W + (i4*4+ii)*128 + co0;
      float4 w0 = *(const float4*)(wp);
      float4 w1 = *(const float4*)(wp + 4);
      float a = av[ii];
      acc[0] += a*w0.x; acc[1] += a*w0.y; acc[2] += a*w0.z; acc[3] += a*w0.w;
      acc[4] += a*w1.x; acc[5] += a*w1.y; acc[6] += a*w1.z; acc[7] += a*w1.w;
    }
  }
}

__device__ __forceinline__ void cvt_copy(float* dst, const void* src, int cnt, bool f32in){
  if (f32in) {
    const float* s = (const float*)src;
    for (int i = threadIdx.x; i < cnt; i += 256) dst[i] = s[i];
  } else {
    const ushort_t* s = (const ushort_t*)src;
    for (int i = threadIdx.x; i < cnt; i += 256) dst[i] = bf1(s[i]);
  }
}

// canonicalize weights + x0 slice to fp32 in ws (handles bf16 OR f32 inputs)
__global__ __launch_bounds__(256) void k_conv(
    const void* times, const void* ca,
    const void* W_h, const void* b_h, const void* W_z, const void* b_z,
    const void* Wf_in, const void* bf_in, const void* Wf_hid, const void* bf_hid,
    const void* Wf_out, const void* bf_out, const void* Wg_in, const void* bg_in,
    const void* Wg_out, const void* bg_out, const void* Eg, const void* W_pool,
    const void* b_pool, char* __restrict__ wsb)
{
  const bool f32in = inputs_are_f32(times);
  float* F = (float*)(wsb + CW_OFF);
  const int bid = blockIdx.x;
  if (bid < 4) {                       // x0 gather: coeff_a[..., 0, :]
    if (bid == 0) for (int i = threadIdx.x; i < 2048; i += 256) g_bar[i] = 0;
    const int base = bid * 4096;
    if (f32in) {
      const float* s = (const float*)ca;
      for (int i = threadIdx.x; i < 4096; i += 256) {
        int g = base + i;
        F[F_X0 + g] = s[(g >> 1)*24 + (g & 1)];
      }
    } else {
      const ushort_t* s = (const ushort_t*)ca;
      for (int i = threadIdx.x; i < 4096; i += 256) {
        int g = base + i;
        F[F_X0 + g] = bf1(s[(g >> 1)*24 + (g & 1)]);
      }
    }
    return;
  }
  if (bid < 20) {                      // W_pool chunk
    const int off = (bid - 4) * 5120;
    const void* srcp = f32in ? (const void*)((const float*)W_pool + off)
                             : (const void*)((const ushort_t*)W_pool + off);
    cvt_copy(F + F_WPOOL + off, srcp, 5120, f32in);
    return;
  }
  const void* src = nullptr; int dst = 0, cnt = 0;
  switch (bid) {
    case 20: src = W_h;    dst = F_WH;    cnt = 128;  break;
    case 21: src = b_h;    dst = F_BH;    cnt = 64;   break;
    case 22: src = W_z;    dst = F_WZ;    cnt = 128;  break;
    case 23: src = b_z;    dst = F_BZ;    cnt = 64;   break;
    case 24: src = Wf_in;  dst = F_WFIN;  cnt = 4096; break;
    case 25: src = bf_in;  dst = F_BFIN;  cnt = 64;   break;
    case 26: src = Wf_hid; dst = F_WFHID; cnt = 4096; break;
    case 27: src = bf_hid; dst = F_BFHID; cnt = 64;   break;
    case 28: src = Wf_out; dst = F_WFOUT; cnt = 8192; break;
    case 29: src = bf_out; dst = F_BFOUT; cnt = 128;  break;
    case 30: src = Wg_in;  dst = F_WGIN;  cnt = 4096; break;
    case 31: src = bg_in;  dst = F_BGIN;  cnt = 64;   break;
    case 32: src = Wg_out; dst = F_WGOUT; cnt = 8192; break;
    case 33: src = bg_out; dst = F_BGOUT; cnt = 128;  break;
    case 34: src = Eg;     dst = F_EG;    cnt = 2560; break;
    default: src = b_pool; dst = F_BPOOL; cnt = 640;  break;
  }
  cvt_copy(F + dst, src, cnt, f32in);
}

// ---------------------------------------------------------------------------
// Persistent fused kernel: prologue (A, Wn, bn, h0/z0, x0) + all 48 RK stages.
// grid 256 x 512. Each block owns rows [bb*256 + nr*32, +32); RK state in regs.
// Cross-block data: only the x exchange (XB) + per-bb spin barrier.
// ---------------------------------------------------------------------------
__global__ __launch_bounds__(512, 2) void k_all(
    const void* __restrict__ times,
    const void* __restrict__ cbv, const void* __restrict__ ccv, const void* __restrict__ cdv,
    char* __restrict__ wsb, float* __restrict__ out)
{
  const float* F  = (const float*)(wsb + CW_OFF);
  uint_t* Wnu = (uint_t*)(wsb + WN_OFF);
  ushort_t* XB = (ushort_t*)(wsb + XB_OFF);
  const bool f32in = inputs_are_f32(times);

  const int tid = threadIdx.x;
  const int lr  = tid >> 4;
  const int t16 = tid & 15;
  const int o0  = t16 * 4;
  const int co0 = o0 * 2;
  const int bb  = blockIdx.x >> 3;
  const int nr  = blockIdx.x & 7;
  const int n   = nr * 32 + lr;
  const int row = bb * 256 + n;

  __shared__ __align__(16) float sIn[32][68];
  __shared__ __align__(16) float sT [32][68];
  __shared__ __align__(16) float sX [32][68];
  __shared__ __align__(16) float xs [128][68];
  __shared__ __align__(16) float sA [32][260];   // pad 260: breaks 4-way bank alias, keeps 16B align

  // ---- prologue (a): A row softmax into sA, bn into regs -------------------
  float eg_n[10];
  #pragma unroll
  for (int d = 0; d < 10; ++d) eg_n[d] = F[F_EG + n*10 + d];
  {
    float ex[16]; float vmax = -1e30f;
    #pragma unroll
    for (int j = 0; j < 16; ++j) {
      int m = t16*16 + j;
      float dot = 0.f;
      #pragma unroll
      for (int d = 0; d < 10; ++d) dot += eg_n[d] * F[F_EG + m*10 + d];
      float v = fmaxf(dot, 0.f);
      ex[j] = v; vmax = fmaxf(vmax, v);
    }
    #pragma unroll
    for (int off = 8; off; off >>= 1) vmax = fmaxf(vmax, __shfl_xor(vmax, off, 16));
    float ssum = 0.f;
    #pragma unroll
    for (int j = 0; j < 16; ++j) { ex[j] = __expf(ex[j] - vmax); ssum += ex[j]; }
    #pragma unroll
    for (int off = 8; off; off >>= 1) ssum += __shfl_xor(ssum, off, 16);
    float inv = 1.f / ssum;
    #pragma unroll
    for (int j = 0; j < 16; ++j) sA[lr][t16*16 + j] = ex[j] * inv;
  }
  float bnr[4];
  #pragma unroll
  for (int j = 0; j < 4; ++j) {
    float acc = 0.f;
    #pragma unroll
    for (int d = 0; d < 10; ++d) acc += eg_n[d] * F[F_BPOOL + d*64 + o0 + j];
    bnr[j] = acc;
  }

  // ---- prologue (b): this block's 32-n Wn slice (bf16, stays in own L2) ----
  #pragma unroll 1
  for (int u = tid; u < 131072; u += 512) {
    int o2 = u & 31, i = (u >> 5) & 63, k = (u >> 11) & 1, ln = u >> 12;
    int n2 = nr*32 + ln;
    const float* egp = F + F_EG + n2*10;
    float a0 = 0.f, a1 = 0.f;
    #pragma unroll
    for (int d = 0; d < 10; ++d) {
      const float* w = F + F_WPOOL + ((d*2 + k)*64 + i)*64 + o2*2;
      float e = egp[d];
      a0 += e*w[0]; a1 += e*w[1];
    }
    Wnu[n2*4096 + k*2048 + i*32 + o2] = f2bf(a0) | (f2bf(a1) << 16);
  }

  // ---- hoist biases --------------------------------------------------------
  float bgin[4], bfin[4], bfhid[4], bfout[8], bgout[8];
  { float4 v = *(const float4*)(F + F_BGIN  + o0); bgin[0]=v.x; bgin[1]=v.y; bgin[2]=v.z; bgin[3]=v.w; }
  { float4 v = *(const float4*)(F + F_BFIN  + o0); bfin[0]=v.x; bfin[1]=v.y; bfin[2]=v.z; bfin[3]=v.w; }
  { float4 v = *(const float4*)(F + F_BFHID + o0); bfhid[0]=v.x; bfhid[1]=v.y; bfhid[2]=v.z; bfhid[3]=v.w; }
  { float4 v0 = *(const float4*)(F + F_BFOUT + co0); float4 v1 = *(const float4*)(F + F_BFOUT + co0 + 4);
    bfout[0]=v0.x; bfout[1]=v0.y; bfout[2]=v0.z; bfout[3]=v0.w; bfout[4]=v1.x; bfout[5]=v1.y; bfout[6]=v1.z; bfout[7]=v1.w; }
  { float4 v0 = *(const float4*)(F + F_BGOUT + co0); float4 v1 = *(const float4*)(F + F_BGOUT + co0 + 4);
    bgout[0]=v0.x; bgout[1]=v0.y; bgout[2]=v0.z; bgout[3]=v0.w; bgout[4]=v1.x; bgout[5]=v1.y; bgout[6]=v1.z; bgout[7]=v1.w; }

  // ---- prologue (c): h0, z0, out[t=0], x0 ----------------------------------
  float h[4], z[4], uh[4], Qh[4], Qz[4], Ph[4], Pz[4];
  {
    float a0 = F[F_X0 + row*2 + 0];
    float a1 = F[F_X0 + row*2 + 1];
    #pragma unroll
    for (int j = 0; j < 4; ++j) {
      h[j] = a0*F[F_WH + o0+j] + a1*F[F_WH + 64+o0+j] + F[F_BH + o0+j];
      z[j] = a0*F[F_WZ + o0+j] + a1*F[F_WZ + 64+o0+j] + F[F_BZ + o0+j];
      uh[j] = h[j]; Qh[j]=0.f; Qz[j]=0.f; Ph[j]=0.f; Pz[j]=0.f;
    }
    ntst4(out + (row*13)*64 + o0, z[0],z[1],z[2],z[3]);
    __syncthreads();
    *(float4*)&sIn[lr][o0] = make_float4(z[0],z[1],z[2],z[3]);
    __syncthreads();
    float xr[4] = {bgin[0],bgin[1],bgin[2],bgin[3]};
    dotf_4(&sIn[lr][0], F + F_WGIN, o0, xr);
    #pragma unroll
    for (int j = 0; j < 4; ++j) xr[j] = fmaxf(xr[j], 0.f);
    u64_t pk = (u64_t)(f2bf(xr[0]) | (f2bf(xr[1]) << 16))
             | ((u64_t)(f2bf(xr[2]) | (f2bf(xr[3]) << 16)) << 32);
    xstore(XB + row*64 + o0, pk);
  }

  // per-bb barrier: 8 arrivals per use, monotone counter
  int* barp = &g_bar[bb*64];
  int bcnt = 0;
  #define BB_BARRIER()  do { \
    __syncthreads(); \
    ++bcnt; \
    if (tid == 0) { \
      atomicAdd(barp, 1); \
      while (__hip_atomic_load(barp, __ATOMIC_RELAXED, __HIP_MEMORY_SCOPE_AGENT) < 8*bcnt) \
        __builtin_amdgcn_s_sleep(2); \
    } \
    __syncthreads(); \
  } while (0)

  BB_BARRIER();   // x0 visible to all blocks of bb

  const uint_t* W0u = Wnu + n*4096;

  // ---- 48 vector-field stages ---------------------------------------------
  #pragma unroll 1
  for (int vfc = 0; vfc < 48; ++vfc) {
    const int s  = vfc >> 2;
    const int st = vfc & 3;
    const ushort_t* Xc = XB + (vfc & 1) * 524288;
    ushort_t*       Xn = XB + ((vfc + 1) & 1) * 524288;

    // own x row
    { u64_t w8 = xload(Xc + row*64 + o0);
      uint_t wl = (uint_t)w8, wh = (uint_t)(w8 >> 32);
      *(float4*)&sX[lr][o0] = make_float4(bfl(wl), bfh(wl), bfl(wh), bfh(wh)); }

    // graph conv: y[n] = A[n,:] @ x[bb,:,:]  (two 128-row halves through LDS)
    float y[4] = {0.f,0.f,0.f,0.f};
    #pragma unroll 1
    for (int half = 0; half < 2; ++half) {
      __syncthreads();
      #pragma unroll
      for (int q = tid; q < 2048; q += 512) {
        int r = q >> 4, c4 = q & 15;
        u64_t w8 = xload(Xc + (bb*256 + half*128 + r)*64 + c4*4);
        uint_t wl = (uint_t)w8, wh = (uint_t)(w8 >> 32);
        *(float4*)&xs[r][c4*4] = make_float4(bfl(wl), bfh(wl), bfl(wh), bfh(wh));
      }
      __syncthreads();
      #pragma unroll 4
      for (int m4 = 0; m4 < 32; ++m4) {
        float4 av = *(const float4*)&sA[lr][half*128 + m4*4];
        float am[4] = {av.x, av.y, av.z, av.w};
        #pragma unroll
        for (int mm = 0; mm < 4; ++mm) {
          float4 xv = *(const float4*)&xs[m4*4+mm][o0];
          y[0] += am[mm]*xv.x; y[1] += am[mm]*xv.y;
          y[2] += am[mm]*xv.z; y[3] += am[mm]*xv.w;
        }
      }
    }

    // og = bn[n] + x@Wn[n,0] + y@Wn[n,1]
    __syncthreads();
    *(float4*)&sT[lr][o0] = make_float4(y[0],y[1],y[2],y[3]);
    __syncthreads();
    float og[4] = {bnr[0], bnr[1], bnr[2], bnr[3]};
    #pragma unroll
    for (int i4 = 0; i4 < 16; ++i4) {
      float4 xa = *(const float4*)&sX[lr][i4*4];
      float4 ya = *(const float4*)&sT[lr][i4*4];
      float xav[4]={xa.x,xa.y,xa.z,xa.w};
      float yav[4]={ya.x,ya.y,ya.z,ya.w};
      #pragma unroll
      for (int ii = 0; ii < 4; ++ii) {
        int i = i4*4 + ii;
        uint2 w0 = *(const uint2*)(W0u + i*32 + (o0 >> 1));
        uint2 w1 = *(const uint2*)(W0u + 2048 + i*32 + (o0 >> 1));
        og[0] += xav[ii]*bfl(w0.x) + yav[ii]*bfl(w1.x);
        og[1] += xav[ii]*bfh(w0.x) + yav[ii]*bfh(w1.x);
        og[2] += xav[ii]*bfl(w0.y) + yav[ii]*bfl(w1.y);
        og[3] += xav[ii]*bfh(w0.y) + yav[ii]*bfh(w1.y);
      }
    }
    *(float4*)&sIn[lr][o0] = make_float4(og[0],og[1],og[2],og[3]);
    __syncthreads();
    float go[8] = {bgout[0],bgout[1],bgout[2],bgout[3],bgout[4],bgout[5],bgout[6],bgout[7]};
    dotf_8(&sIn[lr][0], F + F_WGOUT, co0, go);
    float g0[4], g1[4];
    #pragma unroll
    for (int j=0;j<4;++j){ g0[j]=fast_tanh(go[2*j]); g1[j]=fast_tanh(go[2*j+1]); }

    // f-path from uh (registers)
    __syncthreads();                       // dotf_8 reads of sIn done
    *(float4*)&sIn[lr][o0] = make_float4(uh[0],uh[1],uh[2],uh[3]);
    __syncthreads();
    float a1v[4] = {bfin[0],bfin[1],bfin[2],bfin[3]};
    dotf_4(&sIn[lr][0], F + F_WFIN, o0, a1v);
    #pragma unroll
    for (int j=0;j<4;++j) a1v[j] = fmaxf(a1v[j], 0.f);
    *(float4*)&sT[lr][o0] = make_float4(a1v[0],a1v[1],a1v[2],a1v[3]);
    __syncthreads();
    float a2v[4] = {bfhid[0],bfhid[1],bfhid[2],bfhid[3]};
    dotf_4(&sT[lr][0], F + F_WFHID, o0, a2v);
    #pragma unroll
    for (int j=0;j<4;++j) a2v[j] = fmaxf(a2v[j], 0.f);
    *(float4*)&sIn[lr][o0] = make_float4(a2v[0],a2v[1],a2v[2],a2v[3]);
    __syncthreads();
    float fo[8] = {bfout[0],bfout[1],bfout[2],bfout[3],bfout[4],bfout[5],bfout[6],bfout[7]};
    dotf_8(&sIn[lr][0], F + F_WFOUT, co0, fo);
    float f0[4], f1[4];
    #pragma unroll
    for (int j=0;j<4;++j){ f0[j]=fast_tanh(fo[2*j]); f1[j]=fast_tanh(fo[2*j+1]); }

    // dX at this stage's time
    int sidx; float frac;
    if (st == 0)      { sidx = s; frac = 0.f; }
    else if (st == 1) { sidx = s; frac = 0.33333334f; }
    else if (st == 2) { sidx = s; frac = 0.66666669f; }
    else              { sidx = (s < 11) ? s+1 : 11; frac = (s < 11) ? 0.f : 1.f; }
    float dX0, dX1;
    if (f32in) {
      float2 vb = *(const float2*)((const float*)cbv + (row*12 + sidx)*2);
      float2 vc = *(const float2*)((const float*)ccv + (row*12 + sidx)*2);
      float2 vd = *(const float2*)((const float*)cdv + (row*12 + sidx)*2);
      dX0 = vb.x + (vc.x + vd.x*frac)*frac;
      dX1 = vb.y + (vc.y + vd.y*frac)*frac;
    } else {
      uint_t vb = *(const uint_t*)((const ushort_t*)cbv + (row*12 + sidx)*2);
      uint_t vc = *(const uint_t*)((const ushort_t*)ccv + (row*12 + sidx)*2);
      uint_t vd = *(const uint_t*)((const ushort_t*)cdv + (row*12 + sidx)*2);
      dX0 = bfl(vb) + (bfl(vc) + bfl(vd)*frac)*frac;
      dX1 = bfh(vb) + (bfh(vc) + bfh(vd)*frac)*frac;
    }

    float dh[4], dz[4], uz[4];
    #pragma unroll
    for (int j=0;j<4;++j){
      dh[j] = f0[j]*dX0 + f1[j]*dX1;
      dz[j] = g0[j]*f0[j]*dX0 + g1[j]*f1[j]*dX1;
    }

    // RK state update — all in registers
    if (st == 0) {
      #pragma unroll
      for (int j=0;j<4;++j){
        Qh[j]=dh[j]; Qz[j]=dz[j];
        uh[j]=h[j]+dh[j]*(1.f/3.f); uz[j]=z[j]+dz[j]*(1.f/3.f);
      }
    } else if (st == 1) {
      #pragma unroll
      for (int j=0;j<4;++j){
        Ph[j]=Qh[j]-dh[j]; Pz[j]=Qz[j]-dz[j];
        uh[j]=h[j]+dh[j]-Qh[j]*(1.f/3.f);
        uz[j]=z[j]+dz[j]-Qz[j]*(1.f/3.f);
        Qh[j]+=3.f*dh[j]; Qz[j]+=3.f*dz[j];
      }
    } else if (st == 2) {
      #pragma unroll
      for (int j=0;j<4;++j){
        uh[j]=h[j]+Ph[j]+dh[j]; uz[j]=z[j]+Pz[j]+dz[j];
        Qh[j]+=3.f*dh[j]; Qz[j]+=3.f*dz[j];
      }
    } else {
      #pragma unroll
      for (int j=0;j<4;++j){
        h[j] = h[j] + 0.125f*(Qh[j] + dh[j]);
        z[j] = z[j] + 0.125f*(Qz[j] + dz[j]);
        uh[j]=h[j]; uz[j]=z[j];
      }
      ntst4(out + (row*13 + s + 1)*64 + o0, z[0],z[1],z[2],z[3]);
    }

    if (vfc < 47) {
      // x_{v+1} = relu(uz @ Wg_in + bg_in)
      __syncthreads();                     // dotf_8(fo) reads of sIn done
      *(float4*)&sIn[lr][o0] = make_float4(uz[0],uz[1],uz[2],uz[3]);
      __syncthreads();
      float xr[4] = {bgin[0],bgin[1],bgin[2],bgin[3]};
      dotf_4(&sIn[lr][0], F + F_WGIN, o0, xr);
      #pragma unroll
      for (int j=0;j<4;++j) xr[j] = fmaxf(xr[j], 0.f);
      u64_t pk = (u64_t)(f2bf(xr[0]) | (f2bf(xr[1]) << 16))
               | ((u64_t)(f2bf(xr[2]) | (f2bf(xr[3]) << 16)) << 32);
      xstore(Xn + row*64 + o0, pk);
      BB_BARRIER();                        // all bb-blocks wrote x_{v+1}
    }
  }
  #undef BB_BARRIER
}

extern "C" void kernel_launch(void* const* d_in, const int* in_sizes, int n_in,
                              void* d_out, int out_size, void* d_ws, size_t ws_size,
                              hipStream_t stream) {
  const void* times   = d_in[0];
  const void* coeff_a = d_in[1];
  const void* coeff_b = d_in[2];
  const void* coeff_c = d_in[3];
  const void* coeff_d = d_in[4];
  const void* W_h    = d_in[5];
  const void* b_h    = d_in[6];
  const void* W_z    = d_in[7];
  const void* b_z    = d_in[8];
  const void* Wf_in  = d_in[9];
  const void* bf_in  = d_in[10];
  const void* Wf_hid = d_in[11];
  const void* bf_hid = d_in[12];
  const void* Wf_out = d_in[13];
  const void* bf_out = d_in[14];
  const void* Wg_in  = d_in[15];
  const void* bg_in  = d_in[16];
  const void* Eg     = d_in[17];
  const void* W_pool = d_in[18];
  const void* b_pool = d_in[19];
  const void* Wg_out = d_in[20];
  const void* bg_out = d_in[21];

  char* wsb = (char*)d_ws;
  float* out = (float*)d_out;

  hipLaunchKernelGGL(k_conv, dim3(36), dim3(256), 0, stream,
                     times, coeff_a, W_h, b_h, W_z, b_z,
                     Wf_in, bf_in, Wf_hid, bf_hid, Wf_out, bf_out,
                     Wg_in, bg_in, Wg_out, bg_out, Eg, W_pool, b_pool, wsb);
  // grid 256 x 512, ~94 KB LDS -> exactly 1 block/CU on 256 CUs: all blocks
  // co-resident by capacity; per-bb spin barriers are deadlock-free.
  hipLaunchKernelGGL(k_all, dim3(256), dim3(512), 0, stream,
                     times, coeff_b, coeff_c, coeff_d, wsb, out);
}

// Round 7
// 9243.967 us; speedup vs baseline: 2.5610x; 2.5610x over previous
//
#include <hip/hip_runtime.h>

typedef unsigned short ushort_t;
typedef unsigned int uint_t;
typedef float f4v __attribute__((ext_vector_type(4)));

// Problem dims: B=32 N=256 T=13 CIN=2 HID=64 EMB=10 K=2
// Output: float32, (B,N,13,HID)
// ws layout (21,823,488 B footprint, unchanged):
#define CW_OFF  0          // canonical fp32 inputs (524288 B)
#define A_OFF   524288     // A  fp32 256x256
#define BN_OFF  786432     // bn fp32 256x64
#define WN_OFF  851968     // Wn bf16 256x2x64x64 (4 MB)
#define XB_OFF  5046272    // XB bf16 2 x (8192x64) x-exchange double buffer
#define H_OFF   7143424    // H  fp32 8192x64
#define Z_OFF   9240576    // Z  fp32 8192x64
#define K1H_OFF 11337728
#define K1Z_OFF 13434880
#define K2H_OFF 15532032
#define K2Z_OFF 17629184
#define UH_OFF  19726336

// float-element offsets inside canonical region F
#define F_X0     0
#define F_WH     16384
#define F_BH     16512
#define F_WZ     16576
#define F_BZ     16704
#define F_WFIN   16768
#define F_BFIN   20864
#define F_WFHID  20928
#define F_BFHID  25024
#define F_WFOUT  25088
#define F_BFOUT  33280
#define F_WGIN   33408
#define F_BGIN   37504
#define F_WGOUT  37568
#define F_BGOUT  45760
#define F_EG     45888
#define F_WPOOL  48448
#define F_BPOOL  130368

__device__ __forceinline__ float bfl(uint_t u){ union{uint_t i; float f;} c; c.i = u<<16; return c.f; }
__device__ __forceinline__ float bfh(uint_t u){ union{uint_t i; float f;} c; c.i = u & 0xffff0000u; return c.f; }
__device__ __forceinline__ float bf1(ushort_t u){ union{uint_t i; float f;} c; c.i = ((uint_t)u)<<16; return c.f; }
__device__ __forceinline__ uint_t f2bf(float x){
  uint_t u = __float_as_uint(x);
  uint_t r = u + 0x7fffu + ((u >> 16) & 1u);
  return r >> 16;
}
__device__ __forceinline__ float fast_tanh(float x){
  float e = __expf(2.0f*x);
  return 1.0f - 2.0f/(e+1.0f);
}
// input dtype probe: times = arange(T). bf16 -> word0 = 0x3F800000; f32 -> 0x00000000
__device__ __forceinline__ bool inputs_are_f32(const void* times){
  return ((const uint_t*)times)[0] != 0x3F800000u;
}
__device__ __forceinline__ void ntst4(float* p, float a, float b, float c, float d){
  f4v v; v[0]=a; v[1]=b; v[2]=c; v[3]=d;
  __builtin_nontemporal_store(v, (f4v*)p);
}

// acc[0..3] += sum_i act[i] * W[i*64 + o0 + j]   (W fp32, row stride 64)
__device__ __forceinline__ void dotf_4(const float* act, const float* W, int o0, float acc[4]) {
  const float4* a4 = (const float4*)act;
  #pragma unroll
  for (int i4 = 0; i4 < 16; ++i4) {
    float4 av4 = a4[i4];
    float av[4] = {av4.x, av4.y, av4.z, av4.w};
    #pragma unroll
    for (int ii = 0; ii < 4; ++ii) {
      float4 w = *(const float4*)(W + (i4*4+ii)*64 + o0);
      acc[0] += av[ii]*w.x; acc[1] += av[ii]*w.y;
      acc[2] += av[ii]*w.z; acc[3] += av[ii]*w.w;
    }
  }
}

// acc[0..7] += sum_i act[i] * W[i*128 + co0 + j]  (W fp32, row stride 128)
__device__ __forceinline__ void dotf_8(const float* act, const float* W, int co0, float acc[8]) {
  const float4* a4 = (const float4*)act;
  #pragma unroll
  for (int i4 = 0; i4 < 16; ++i4) {
    float4 av4 = a4[i4];
    float av[4] = {av4.x, av4.y, av4.z, av4.w};
    #pragma unroll
    for (int ii = 0; ii < 4; ++ii) {
      const float* wp = W + (i4*4+ii)*128 + co0;
      float4 w0 = *(const float4*)(wp);
      float4 w1 = *(const float4*)(wp + 4);
      float a = av[ii];
      acc[0] += a*w0.x; acc[1] += a*w0.y; acc[2] += a*w0.z; acc[3] += a*w0.w;
      acc[4] += a*w1.x; acc[5] += a*w1.y; acc[6] += a*w1.z; acc[7] += a*w1.w;
    }
  }
}

__device__ __forceinline__ void cvt_copy(float* dst, const void* src, int cnt, bool f32in){
  if (f32in) {
    const float* s = (const float*)src;
    for (int i = threadIdx.x; i < cnt; i += 256) dst[i] = s[i];
  } else {
    const ushort_t* s = (const ushort_t*)src;
    for (int i = threadIdx.x; i < cnt; i += 256) dst[i] = bf1(s[i]);
  }
}

// canonicalize weights + x0 slice to fp32 in ws (bf16 OR f32 inputs)
// grid 36: bid 0..3 x0 quarters; 4..19 W_pool chunks; 20..35 small tensors
__global__ __launch_bounds__(256) void k_conv(
    const void* times, const void* ca,
    const void* W_h, const void* b_h, const void* W_z, const void* b_z,
    const void* Wf_in, const void* bf_in, const void* Wf_hid, const void* bf_hid,
    const void* Wf_out, const void* bf_out, const void* Wg_in, const void* bg_in,
    const void* Wg_out, const void* bg_out, const void* Eg, const void* W_pool,
    const void* b_pool, char* __restrict__ wsb)
{
  const bool f32in = inputs_are_f32(times);
  float* F = (float*)(wsb + CW_OFF);
  const int bid = blockIdx.x;
  if (bid < 4) {                       // x0 gather: coeff_a[..., 0, :]
    const int base = bid * 4096;
    if (f32in) {
      const float* s = (const float*)ca;
      for (int i = threadIdx.x; i < 4096; i += 256) {
        int g = base + i;
        F[F_X0 + g] = s[(g >> 1)*24 + (g & 1)];
      }
    } else {
      const ushort_t* s = (const ushort_t*)ca;
      for (int i = threadIdx.x; i < 4096; i += 256) {
        int g = base + i;
        F[F_X0 + g] = bf1(s[(g >> 1)*24 + (g & 1)]);
      }
    }
    return;
  }
  if (bid < 20) {                      // W_pool chunk
    const int off = (bid - 4) * 5120;
    const void* srcp = f32in ? (const void*)((const float*)W_pool + off)
                             : (const void*)((const ushort_t*)W_pool + off);
    cvt_copy(F + F_WPOOL + off, srcp, 5120, f32in);
    return;
  }
  const void* src = nullptr; int dst = 0, cnt = 0;
  switch (bid) {
    case 20: src = W_h;    dst = F_WH;    cnt = 128;  break;
    case 21: src = b_h;    dst = F_BH;    cnt = 64;   break;
    case 22: src = W_z;    dst = F_WZ;    cnt = 128;  break;
    case 23: src = b_z;    dst = F_BZ;    cnt = 64;   break;
    case 24: src = Wf_in;  dst = F_WFIN;  cnt = 4096; break;
    case 25: src = bf_in;  dst = F_BFIN;  cnt = 64;   break;
    case 26: src = Wf_hid; dst = F_WFHID; cnt = 4096; break;
    case 27: src = bf_hid; dst = F_BFHID; cnt = 64;   break;
    case 28: src = Wf_out; dst = F_WFOUT; cnt = 8192; break;
    case 29: src = bf_out; dst = F_BFOUT; cnt = 128;  break;
    case 30: src = Wg_in;  dst = F_WGIN;  cnt = 4096; break;
    case 31: src = bg_in;  dst = F_BGIN;  cnt = 64;   break;
    case 32: src = Wg_out; dst = F_WGOUT; cnt = 8192; break;
    case 33: src = bg_out; dst = F_BGOUT; cnt = 128;  break;
    case 34: src = Eg;     dst = F_EG;    cnt = 2560; break;
    default: src = b_pool; dst = F_BPOOL; cnt = 640;  break;
  }
  cvt_copy(F + dst, src, cnt, f32in);
}

// A = softmax(relu(Eg @ Eg^T), axis=1) ; bn = Eg @ b_pool
__global__ __launch_bounds__(256) void k_A(char* __restrict__ wsb) {
  const float* F = (const float*)(wsb + CW_OFF);
  float* Aw = (float*)(wsb + A_OFF);
  float* bn = (float*)(wsb + BN_OFF);
  const int nrow = blockIdx.x;
  const int m = threadIdx.x;
  float eg_n[10];
  #pragma unroll
  for (int d = 0; d < 10; ++d) eg_n[d] = F[F_EG + nrow*10 + d];
  float dot = 0.f;
  #pragma unroll
  for (int d = 0; d < 10; ++d) dot += eg_n[d] * F[F_EG + m*10 + d];
  float v = fmaxf(dot, 0.f);
  __shared__ float red[256];
  red[m] = v; __syncthreads();
  for (int off = 128; off > 0; off >>= 1) {
    if (m < off) red[m] = fmaxf(red[m], red[m+off]);
    __syncthreads();
  }
  float vmax = red[0]; __syncthreads();
  float e = __expf(v - vmax);
  red[m] = e; __syncthreads();
  for (int off = 128; off > 0; off >>= 1) {
    if (m < off) red[m] += red[m+off];
    __syncthreads();
  }
  float ssum = red[0];
  Aw[nrow*256 + m] = e / ssum;
  if (m < 64) {
    float acc = 0.f;
    #pragma unroll
    for (int d = 0; d < 10; ++d) acc += eg_n[d] * F[F_BPOOL + d*64 + m];
    bn[nrow*64 + m] = acc;
  }
}

// Wn[n][k][i][o] = sum_d Eg[n,d] * W_pool[d,k,i,o]   (stored bf16)
__global__ __launch_bounds__(256) void k_Wn(char* __restrict__ wsb) {
  const float* F = (const float*)(wsb + CW_OFF);
  ushort_t* Wn = (ushort_t*)(wsb + WN_OFF);
  int idx = blockIdx.x*256 + threadIdx.x;   // < 2097152
  int o = idx & 63;
  int i = (idx >> 6) & 63;
  int k = (idx >> 12) & 1;
  int n = idx >> 13;
  float acc = 0.f;
  #pragma unroll
  for (int d = 0; d < 10; ++d)
    acc += F[F_EG + n*10 + d] * F[F_WPOOL + ((d*2 + k)*64 + i)*64 + o];
  Wn[idx] = (ushort_t)f2bf(acc);
}

// h0,z0; out t=0 (fp32); x_0 = relu(z0@Wg_in+bg_in) -> XB buf0
__global__ __launch_bounds__(512) void k_init2(char* __restrict__ wsb, float* __restrict__ out) {
  const float* F = (const float*)(wsb + CW_OFF);
  float* H = (float*)(wsb + H_OFF);
  float* Z = (float*)(wsb + Z_OFF);
  ushort_t* X0 = (ushort_t*)(wsb + XB_OFF);   // buffer 0

  const int tid = threadIdx.x;
  const int lr  = tid >> 4;
  const int o0  = (tid & 15) * 4;
  const int row = blockIdx.x * 32 + lr;

  __shared__ __align__(16) float sIn[32][68];

  float a0 = F[F_X0 + row*2 + 0];
  float a1 = F[F_X0 + row*2 + 1];
  float h[4], z[4];
  #pragma unroll
  for (int j = 0; j < 4; ++j) {
    h[j] = a0*F[F_WH + o0+j] + a1*F[F_WH + 64+o0+j] + F[F_BH + o0+j];
    z[j] = a0*F[F_WZ + o0+j] + a1*F[F_WZ + 64+o0+j] + F[F_BZ + o0+j];
  }
  *(float4*)(H + row*64 + o0) = make_float4(h[0],h[1],h[2],h[3]);
  *(float4*)(Z + row*64 + o0) = make_float4(z[0],z[1],z[2],z[3]);
  ntst4(out + (row*13)*64 + o0, z[0],z[1],z[2],z[3]);

  *(float4*)&sIn[lr][o0] = make_float4(z[0],z[1],z[2],z[3]);
  __syncthreads();
  float xr[4];
  { float4 bv = *(const float4*)(F + F_BGIN + o0);
    xr[0]=bv.x; xr[1]=bv.y; xr[2]=bv.z; xr[3]=bv.w; }
  dotf_4(&sIn[lr][0], F + F_WGIN, o0, xr);
  #pragma unroll
  for (int j=0;j<4;++j) xr[j] = fmaxf(xr[j], 0.f);
  { uint2 pk;
    pk.x = f2bf(xr[0]) | (f2bf(xr[1]) << 16);
    pk.y = f2bf(xr[2]) | (f2bf(xr[3]) << 16);
    *(uint2*)(X0 + row*64 + o0) = pk; }
}

// ---------------------------------------------------------------------------
// One vector-field stage. grid 512 x 512 threads; block = 16 rows of one bb.
// Threads 0..255   (g-half): graph conv -> Wn mix -> Wg_out -> state update.
// Threads 256..511 (f-half): 3-layer f-MLP from uh, dX, p0/p1 -> LDS.
// Uniform top-level __syncthreads between phases; no cross-block sync.
// ---------------------------------------------------------------------------
__global__ __launch_bounds__(512, 4) void k_stage(
    const void* __restrict__ times,
    const void* __restrict__ cbv, const void* __restrict__ ccv, const void* __restrict__ cdv,
    char* __restrict__ wsb, float* __restrict__ out, int vfc)
{
  const float* F  = (const float*)(wsb + CW_OFF);
  const float* Aw = (const float*)(wsb + A_OFF);
  const float* bn = (const float*)(wsb + BN_OFF);
  const ushort_t* Wn = (const ushort_t*)(wsb + WN_OFF);
  ushort_t* XB = (ushort_t*)(wsb + XB_OFF);
  float* H   = (float*)(wsb + H_OFF);
  float* Z   = (float*)(wsb + Z_OFF);
  float* K1h = (float*)(wsb + K1H_OFF);
  float* K1z = (float*)(wsb + K1Z_OFF);
  float* K2h = (float*)(wsb + K2H_OFF);
  float* K2z = (float*)(wsb + K2Z_OFF);
  float* UH  = (float*)(wsb + UH_OFF);
  const bool f32in = inputs_are_f32(times);

  const int s  = vfc >> 2;
  const int st = vfc & 3;
  const ushort_t* Xc = XB + (vfc & 1) * 524288;
  ushort_t*       Xn = XB + ((vfc + 1) & 1) * 524288;

  const int tid = threadIdx.x;
  const bool isF = tid >= 256;
  const int ht  = tid & 255;
  const int lr  = ht >> 4;          // 0..15
  const int t16 = ht & 15;
  const int o0  = t16 * 4;
  const int co0 = o0 * 2;
  const int bb  = blockIdx.x >> 4;  // 0..31
  const int bq  = blockIdx.x & 15;  // 0..15
  const int n   = bq * 16 + lr;     // 0..255
  const int row = bb * 256 + n;

  __shared__ __align__(16) float xs [128][68];
  __shared__ __align__(16) float sX [16][68];
  __shared__ __align__(16) float sY [16][68];
  __shared__ __align__(16) float sOG[16][68];
  __shared__ __align__(16) float sUH[16][68];
  __shared__ __align__(16) float sFA[16][68];   // f L1 out; later reused as sUZ
  __shared__ __align__(16) float sFB[16][68];
  __shared__ __align__(16) float sF0[16][68];   // p0 = f0*dX0
  __shared__ __align__(16) float sF1[16][68];   // p1 = f1*dX1

  // ---- P0: f stages xs rows 0..127 + uh; g loads own x row ----------------
  if (isF) {
    #pragma unroll
    for (int q = ht; q < 2048; q += 256) {
      int r = q >> 4, c4 = (q & 15) * 4;
      uint2 w = *(const uint2*)(Xc + (bb*256 + r)*64 + c4);
      *(float4*)&xs[r][c4] = make_float4(bfl(w.x), bfh(w.x), bfl(w.y), bfh(w.y));
    }
    const float* UHsrc = (st == 0) ? H : UH;
    *(float4*)&sUH[lr][o0] = *(const float4*)(UHsrc + row*64 + o0);
  } else {
    uint2 w = *(const uint2*)(Xc + row*64 + o0);
    *(float4*)&sX[lr][o0] = make_float4(bfl(w.x), bfh(w.x), bfl(w.y), bfh(w.y));
  }
  __syncthreads();

  float y[4] = {0.f, 0.f, 0.f, 0.f};   // g: conv accumulator (lives P1..P3)

  // ---- P1: g conv half 1; f L1 --------------------------------------------
  if (isF) {
    float a1v[4];
    { float4 bv = *(const float4*)(F + F_BFIN + o0);
      a1v[0]=bv.x; a1v[1]=bv.y; a1v[2]=bv.z; a1v[3]=bv.w; }
    dotf_4(&sUH[lr][0], F + F_WFIN, o0, a1v);
    #pragma unroll
    for (int j = 0; j < 4; ++j) a1v[j] = fmaxf(a1v[j], 0.f);
    *(float4*)&sFA[lr][o0] = make_float4(a1v[0],a1v[1],a1v[2],a1v[3]);
  } else {
    const float* Arow = Aw + n*256;
    #pragma unroll 4
    for (int m4 = 0; m4 < 32; ++m4) {
      float4 av = *(const float4*)(Arow + m4*4);
      float am[4] = {av.x, av.y, av.z, av.w};
      #pragma unroll
      for (int mm = 0; mm < 4; ++mm) {
        float4 xv = *(const float4*)&xs[m4*4+mm][o0];
        y[0] += am[mm]*xv.x; y[1] += am[mm]*xv.y;
        y[2] += am[mm]*xv.z; y[3] += am[mm]*xv.w;
      }
    }
  }
  __syncthreads();

  // ---- P2: g stages xs rows 128..255; f L2 --------------------------------
  if (isF) {
    float a2v[4];
    { float4 bv = *(const float4*)(F + F_BFHID + o0);
      a2v[0]=bv.x; a2v[1]=bv.y; a2v[2]=bv.z; a2v[3]=bv.w; }
    dotf_4(&sFA[lr][0], F + F_WFHID, o0, a2v);
    #pragma unroll
    for (int j = 0; j < 4; ++j) a2v[j] = fmaxf(a2v[j], 0.f);
    *(float4*)&sFB[lr][o0] = make_float4(a2v[0],a2v[1],a2v[2],a2v[3]);
  } else {
    #pragma unroll
    for (int q = ht; q < 2048; q += 256) {
      int r = q >> 4, c4 = (q & 15) * 4;
      uint2 w = *(const uint2*)(Xc + (bb*256 + 128 + r)*64 + c4);
      *(float4*)&xs[r][c4] = make_float4(bfl(w.x), bfh(w.x), bfl(w.y), bfh(w.y));
    }
  }
  __syncthreads();

  // ---- P3: g conv half 2 -> sY; f L3 + dX -> p0/p1 ------------------------
  if (isF) {
    float fo[8];
    { float4 b0 = *(const float4*)(F + F_BFOUT + co0);
      float4 b1 = *(const float4*)(F + F_BFOUT + co0 + 4);
      fo[0]=b0.x; fo[1]=b0.y; fo[2]=b0.z; fo[3]=b0.w;
      fo[4]=b1.x; fo[5]=b1.y; fo[6]=b1.z; fo[7]=b1.w; }
    dotf_8(&sFB[lr][0], F + F_WFOUT, co0, fo);
    float f0[4], f1[4];
    #pragma unroll
    for (int j=0;j<4;++j){ f0[j]=fast_tanh(fo[2*j]); f1[j]=fast_tanh(fo[2*j+1]); }
    // dX at this stage's time
    int sidx; float frac;
    if (st == 0)      { sidx = s; frac = 0.f; }
    else if (st == 1) { sidx = s; frac = 0.33333334f; }
    else if (st == 2) { sidx = s; frac = 0.66666669f; }
    else              { sidx = (s < 11) ? s+1 : 11; frac = (s < 11) ? 0.f : 1.f; }
    float dX0, dX1;
    if (f32in) {
      float2 vb = *(const float2*)((const float*)cbv + (row*12 + sidx)*2);
      float2 vc = *(const float2*)((const float*)ccv + (row*12 + sidx)*2);
      float2 vd = *(const float2*)((const float*)cdv + (row*12 + sidx)*2);
      dX0 = vb.x + (vc.x + vd.x*frac)*frac;
      dX1 = vb.y + (vc.y + vd.y*frac)*frac;
    } else {
      uint_t vb = *(const uint_t*)((const ushort_t*)cbv + (row*12 + sidx)*2);
      uint_t vc = *(const uint_t*)((const ushort_t*)ccv + (row*12 + sidx)*2);
      uint_t vd = *(const uint_t*)((const ushort_t*)cdv + (row*12 + sidx)*2);
      dX0 = bfl(vb) + (bfl(vc) + bfl(vd)*frac)*frac;
      dX1 = bfh(vb) + (bfh(vc) + bfh(vd)*frac)*frac;
    }
    *(float4*)&sF0[lr][o0] = make_float4(f0[0]*dX0, f0[1]*dX0, f0[2]*dX0, f0[3]*dX0);
    *(float4*)&sF1[lr][o0] = make_float4(f1[0]*dX1, f1[1]*dX1, f1[2]*dX1, f1[3]*dX1);
  } else {
    const float* Arow = Aw + n*256 + 128;
    #pragma unroll 4
    for (int m4 = 0; m4 < 32; ++m4) {
      float4 av = *(const float4*)(Arow + m4*4);
      float am[4] = {av.x, av.y, av.z, av.w};
      #pragma unroll
      for (int mm = 0; mm < 4; ++mm) {
        float4 xv = *(const float4*)&xs[m4*4+mm][o0];
        y[0] += am[mm]*xv.x; y[1] += am[mm]*xv.y;
        y[2] += am[mm]*xv.z; y[3] += am[mm]*xv.w;
      }
    }
    *(float4*)&sY[lr][o0] = make_float4(y[0],y[1],y[2],y[3]);
  }
  __syncthreads();

  // ---- P4: g Wn mix -> sOG -------------------------------------------------
  if (!isF) {
    float og[4];
    { float4 bv = *(const float4*)(bn + n*64 + o0); og[0]=bv.x; og[1]=bv.y; og[2]=bv.z; og[3]=bv.w; }
    const ushort_t* W0 = Wn + n*8192;
    #pragma unroll
    for (int i4 = 0; i4 < 16; ++i4) {
      float4 xa = *(const float4*)&sX[lr][i4*4];
      float4 ya = *(const float4*)&sY[lr][i4*4];
      float xav[4]={xa.x,xa.y,xa.z,xa.w};
      float yav[4]={ya.x,ya.y,ya.z,ya.w};
      #pragma unroll
      for (int ii = 0; ii < 4; ++ii) {
        int i = i4*4 + ii;
        uint2 w0 = *(const uint2*)(W0 + i*64 + o0);
        uint2 w1 = *(const uint2*)(W0 + 4096 + i*64 + o0);
        og[0] += xav[ii]*bfl(w0.x) + yav[ii]*bfl(w1.x);
        og[1] += xav[ii]*bfh(w0.x) + yav[ii]*bfh(w1.x);
        og[2] += xav[ii]*bfl(w0.y) + yav[ii]*bfl(w1.y);
        og[3] += xav[ii]*bfh(w0.y) + yav[ii]*bfh(w1.y);
      }
    }
    *(float4*)&sOG[lr][o0] = make_float4(og[0],og[1],og[2],og[3]);
  }
  __syncthreads();

  // ---- P5: g Wg_out, join with p0/p1, state update; uz -> sFA --------------
  if (!isF) {
    float go[8];
    { float4 b0 = *(const float4*)(F + F_BGOUT + co0);
      float4 b1 = *(const float4*)(F + F_BGOUT + co0 + 4);
      go[0]=b0.x; go[1]=b0.y; go[2]=b0.z; go[3]=b0.w;
      go[4]=b1.x; go[5]=b1.y; go[6]=b1.z; go[7]=b1.w; }
    dotf_8(&sOG[lr][0], F + F_WGOUT, co0, go);
    float g0[4], g1[4];
    #pragma unroll
    for (int j=0;j<4;++j){ g0[j]=fast_tanh(go[2*j]); g1[j]=fast_tanh(go[2*j+1]); }

    float4 p0v = *(const float4*)&sF0[lr][o0];
    float4 p1v = *(const float4*)&sF1[lr][o0];
    float p0[4]={p0v.x,p0v.y,p0v.z,p0v.w}, p1[4]={p1v.x,p1v.y,p1v.z,p1v.w};
    float dh[4], dz[4];
    #pragma unroll
    for (int j=0;j<4;++j){
      dh[j] = p0[j] + p1[j];
      dz[j] = g0[j]*p0[j] + g1[j]*p1[j];
    }

    float uh_n[4], uz_n[4];
    float4 hv = *(const float4*)(H + row*64 + o0);
    float4 zv = *(const float4*)(Z + row*64 + o0);
    float h[4] = {hv.x,hv.y,hv.z,hv.w};
    float z[4] = {zv.x,zv.y,zv.z,zv.w};

    if (st == 0) {
      *(float4*)(K1h + row*64 + o0) = make_float4(dh[0],dh[1],dh[2],dh[3]);
      *(float4*)(K1z + row*64 + o0) = make_float4(dz[0],dz[1],dz[2],dz[3]);
      #pragma unroll
      for (int j=0;j<4;++j){ uh_n[j]=h[j]+dh[j]*(1.f/3.f); uz_n[j]=z[j]+dz[j]*(1.f/3.f); }
    } else if (st == 1) {
      float4 k1hv = *(const float4*)(K1h + row*64 + o0);
      float4 k1zv = *(const float4*)(K1z + row*64 + o0);
      float k1hl[4]={k1hv.x,k1hv.y,k1hv.z,k1hv.w};
      float k1zl[4]={k1zv.x,k1zv.y,k1zv.z,k1zv.w};
      float Qh[4],Qz[4],Ph[4],Pz[4];
      #pragma unroll
      for (int j=0;j<4;++j){
        Qh[j]=k1hl[j]+3.f*dh[j]; Qz[j]=k1zl[j]+3.f*dz[j];
        Ph[j]=k1hl[j]-dh[j];     Pz[j]=k1zl[j]-dz[j];
        uh_n[j]=h[j]+dh[j]-k1hl[j]*(1.f/3.f);
        uz_n[j]=z[j]+dz[j]-k1zl[j]*(1.f/3.f);
      }
      *(float4*)(K1h + row*64 + o0) = make_float4(Qh[0],Qh[1],Qh[2],Qh[3]);
      *(float4*)(K1z + row*64 + o0) = make_float4(Qz[0],Qz[1],Qz[2],Qz[3]);
      *(float4*)(K2h + row*64 + o0) = make_float4(Ph[0],Ph[1],Ph[2],Ph[3]);
      *(float4*)(K2z + row*64 + o0) = make_float4(Pz[0],Pz[1],Pz[2],Pz[3]);
    } else if (st == 2) {
      float4 Qhv = *(const float4*)(K1h + row*64 + o0);
      float4 Qzv = *(const float4*)(K1z + row*64 + o0);
      float4 Phv = *(const float4*)(K2h + row*64 + o0);
      float4 Pzv = *(const float4*)(K2z + row*64 + o0);
      float Qh[4]={Qhv.x,Qhv.y,Qhv.z,Qhv.w}, Qz[4]={Qzv.x,Qzv.y,Qzv.z,Qzv.w};
      float Ph[4]={Phv.x,Phv.y,Phv.z,Phv.w}, Pz[4]={Pzv.x,Pzv.y,Pzv.z,Pzv.w};
      float Ah[4],Az[4];
      #pragma unroll
      for (int j=0;j<4;++j){
        Ah[j]=Qh[j]+3.f*dh[j]; Az[j]=Qz[j]+3.f*dz[j];   // k1+3k2+3k3
        uh_n[j]=h[j]+Ph[j]+dh[j];                        // h + k1-k2+k3
        uz_n[j]=z[j]+Pz[j]+dz[j];
      }
      *(float4*)(K1h + row*64 + o0) = make_float4(Ah[0],Ah[1],Ah[2],Ah[3]);
      *(float4*)(K1z + row*64 + o0) = make_float4(Az[0],Az[1],Az[2],Az[3]);
    } else {
      float4 Ahv = *(const float4*)(K1h + row*64 + o0);
      float4 Azv = *(const float4*)(K1z + row*64 + o0);
      #pragma unroll
      for (int j=0;j<4;++j){
        float hn = h[j] + 0.125f*(((const float*)&Ahv)[j] + dh[j]);
        float zn = z[j] + 0.125f*(((const float*)&Azv)[j] + dz[j]);
        uh_n[j]=hn; uz_n[j]=zn;
      }
      *(float4*)(H + row*64 + o0) = make_float4(uh_n[0],uh_n[1],uh_n[2],uh_n[3]);
      *(float4*)(Z + row*64 + o0) = make_float4(uz_n[0],uz_n[1],uz_n[2],uz_n[3]);
      ntst4(out + (row*13 + s + 1)*64 + o0, uz_n[0],uz_n[1],uz_n[2],uz_n[3]);
    }

    if (vfc < 47) {
      *(float4*)(UH + row*64 + o0) = make_float4(uh_n[0],uh_n[1],uh_n[2],uh_n[3]);
      *(float4*)&sFA[lr][o0] = make_float4(uz_n[0],uz_n[1],uz_n[2],uz_n[3]);  // sUZ
    }
  }
  __syncthreads();

  // ---- P6: x_{v+1} = relu(uz @ Wg_in + bg_in), both halves, 2 cols each ---
  if (vfc < 47) {
    const int c = o0 + (isF ? 2 : 0);
    float xr0 = F[F_BGIN + c], xr1 = F[F_BGIN + c + 1];
    #pragma unroll
    for (int i = 0; i < 64; ++i) {
      float a = sFA[lr][i];
      float2 wv = *(const float2*)(F + F_WGIN + i*64 + c);
      xr0 += a*wv.x; xr1 += a*wv.y;
    }
    xr0 = fmaxf(xr0, 0.f); xr1 = fmaxf(xr1, 0.f);
    uint_t pk = f2bf(xr0) | (f2bf(xr1) << 16);
    *(uint_t*)(Xn + row*64 + c) = pk;
  }
}

extern "C" void kernel_launch(void* const* d_in, const int* in_sizes, int n_in,
                              void* d_out, int out_size, void* d_ws, size_t ws_size,
                              hipStream_t stream) {
  const void* times   = d_in[0];
  const void* coeff_a = d_in[1];
  const void* coeff_b = d_in[2];
  const void* coeff_c = d_in[3];
  const void* coeff_d = d_in[4];
  const void* W_h    = d_in[5];
  const void* b_h    = d_in[6];
  const void* W_z    = d_in[7];
  const void* b_z    = d_in[8];
  const void* Wf_in  = d_in[9];
  const void* bf_in  = d_in[10];
  const void* Wf_hid = d_in[11];
  const void* bf_hid = d_in[12];
  const void* Wf_out = d_in[13];
  const void* bf_out = d_in[14];
  const void* Wg_in  = d_in[15];
  const void* bg_in  = d_in[16];
  const void* Eg     = d_in[17];
  const void* W_pool = d_in[18];
  const void* b_pool = d_in[19];
  const void* Wg_out = d_in[20];
  const void* bg_out = d_in[21];

  char* wsb = (char*)d_ws;
  float* out = (float*)d_out;

  hipLaunchKernelGGL(k_conv, dim3(36), dim3(256), 0, stream,
                     times, coeff_a, W_h, b_h, W_z, b_z,
                     Wf_in, bf_in, Wf_hid, bf_hid, Wf_out, bf_out,
                     Wg_in, bg_in, Wg_out, bg_out, Eg, W_pool, b_pool, wsb);
  hipLaunchKernelGGL(k_A,    dim3(256),  dim3(256), 0, stream, wsb);
  hipLaunchKernelGGL(k_Wn,   dim3(8192), dim3(256), 0, stream, wsb);
  hipLaunchKernelGGL(k_init2, dim3(256), dim3(512), 0, stream, wsb, out);
  for (int vfc = 0; vfc < 48; ++vfc) {
    hipLaunchKernelGGL(k_stage, dim3(512), dim3(512), 0, stream,
                       times, coeff_b, coeff_c, coeff_d, wsb, out, vfc);
  }
}